// Round 1
// baseline (395.022 us; speedup 1.0000x reference)
//
#include <hip/hip_runtime.h>
#include <hip/hip_bf16.h>
#include <stdint.h>

// Problem constants
#define NVOX   884736      // 96*96*96 voxels per batch
#define NB     32          // batches
#define NPTS   512         // MAX_POINTS
#define CAP    4096        // candidate capacity per batch
#define THRV   0.9990f     // conservative static threshold: E[count]=885, P(<512) ~ 1e-36

#define C0c  0.28209479177387814f
#define C1c  0.4886025119029199f
#define C2c  0.6307831305050401f
#define SQ3c 1.7320508075688772f

typedef unsigned long long u64;
typedef unsigned int u32;

// ---------------------------------------------------------------------------
// Pass 1: single full scan of x. Collect (bits, idx) of all values >= THRV.
// Bit pattern of non-negative float is order-isomorphic to the value.
// ---------------------------------------------------------------------------
__global__ __launch_bounds__(256) void k_collect(const float* __restrict__ x,
                                                 uint2* __restrict__ cand,
                                                 int* __restrict__ cnt) {
  const int b = blockIdx.y;
  const int t = blockIdx.x * 256 + threadIdx.x;
  const float4 q = reinterpret_cast<const float4*>(x + (size_t)b * NVOX)[t];
  const u32 base = (u32)t * 4u;
  uint2* cb = cand + (size_t)b * CAP;
  if (q.x >= THRV) { int p = atomicAdd(&cnt[b], 1); if (p < CAP) cb[p] = make_uint2(__float_as_uint(q.x), base      ); }
  if (q.y >= THRV) { int p = atomicAdd(&cnt[b], 1); if (p < CAP) cb[p] = make_uint2(__float_as_uint(q.y), base + 1u); }
  if (q.z >= THRV) { int p = atomicAdd(&cnt[b], 1); if (p < CAP) cb[p] = make_uint2(__float_as_uint(q.z), base + 2u); }
  if (q.w >= THRV) { int p = atomicAdd(&cnt[b], 1); if (p < CAP) cb[p] = make_uint2(__float_as_uint(q.w), base + 3u); }
}

// ---------------------------------------------------------------------------
// Combined scalar-path matrix M[16][128] = (W1_0e/4) @ (W2_0e/sqrt(32)) @ (W3_0e/8)
// (all three irreps layers are linear; only the scalar block reaches logits)
// ---------------------------------------------------------------------------
__global__ __launch_bounds__(128) void k_buildM(const float* __restrict__ W1,
                                                const float* __restrict__ W2,
                                                const float* __restrict__ W3,
                                                float* __restrict__ M) {
  __shared__ float T[16 * 64];
  const int t = threadIdx.x;
  const float s1 = 1.0f / (4.0f * sqrtf(32.0f));
  for (int e = t; e < 16 * 64; e += 128) {
    const int u = e >> 6, j = e & 63;
    float s = 0.f;
    for (int k = 0; k < 32; ++k) s += W1[u * 32 + k] * W2[k * 64 + j];
    T[e] = s * s1;
  }
  __syncthreads();
  for (int e = t; e < 16 * 128; e += 128) {
    const int u = e >> 7, v = e & 127;
    float s = 0.f;
    for (int j = 0; j < 64; ++j) s += T[u * 64 + j] * W3[j * 128 + v];
    M[e] = s * 0.125f;
  }
}

// ---------------------------------------------------------------------------
// Pass 2: per batch, exact top-512 by rank over packed keys (bits<<32)|~idx
// (encodes jax.lax.top_k order: value desc, index asc on ties).
// Fallback (under/overflow of the static threshold — never occurs for this
// input): exact fine histogram near 1.0 + re-collect.
// Also computes the center-of-mass reduction.
// ---------------------------------------------------------------------------
__global__ __launch_bounds__(512) void k_select(const float* __restrict__ x,
                                                const uint2* __restrict__ cand,
                                                const int* __restrict__ cnt,
                                                uint2* __restrict__ sel,
                                                float4* __restrict__ comv) {
  const int b = blockIdx.x;
  const int tid = threadIdx.x;
  __shared__ u64 lk[CAP];          // 32 KB: candidate keys (reused as histogram in fallback)
  __shared__ u64 sk[NPTS];         // selected, rank-ordered
  __shared__ float rbuf[8][4];
  __shared__ int sC;
  __shared__ u32 sthr;

  int C = cnt[b];
  if (C >= NPTS && C <= CAP) {
    for (int i = tid; i < C; i += 512) {
      const uint2 cd = cand[(size_t)b * CAP + i];
      lk[i] = ((u64)cd.x << 32) | (u64)(~cd.y);
    }
  } else {
    // ---- fallback: exact threshold via 4096-bin histogram of (0x3F800000-1-bits)>>8
    u32* hist = reinterpret_cast<u32*>(lk);
    for (int i = tid; i < 4096; i += 512) hist[i] = 0u;
    __syncthreads();
    const u32* xb = reinterpret_cast<const u32*>(x) + (size_t)b * NVOX;
    for (int i = tid; i < NVOX; i += 512) {
      const u32 bits = xb[i];
      u32 key;
      if (bits >= 0x3F800000u) key = 0u;
      else { const u32 dd = 0x3F7FFFFFu - bits; key = dd >> 8; if (key > 4095u) key = 4095u; }
      atomicAdd(&hist[key], 1u);
    }
    __syncthreads();
    if (tid == 0) {
      u32 cum = 0; int kt = 4095;
      for (int k = 0; k < 4096; ++k) { cum += hist[k]; if (cum >= (u32)NPTS) { kt = k; break; } }
      sthr = (kt >= 4095) ? 0u : (0x3F800000u - ((u32)(kt + 1) << 8));
      sC = 0;
    }
    __syncthreads();
    const u32 thr = sthr;
    for (int i = tid; i < NVOX; i += 512) {
      const u32 bits = xb[i];
      if (bits >= thr) {
        const int p = atomicAdd(&sC, 1);
        if (p < CAP) lk[p] = ((u64)bits << 32) | (u64)(~(u32)i);
      }
    }
    __syncthreads();
    C = sC < CAP ? sC : CAP;
  }
  __syncthreads();

  // exact rank of each candidate (keys are unique: idx unique)
  for (int i = tid; i < C; i += 512) {
    const u64 ki = lk[i];
    int rank = 0;
    for (int j = 0; j < C; ++j) rank += (lk[j] > ki) ? 1 : 0;
    if (rank < NPTS) sk[rank] = ki;
  }
  __syncthreads();

  const u64 key = sk[tid];
  const u32 bits = (u32)(key >> 32);
  const u32 idx = ~((u32)key);
  sel[(size_t)b * NPTS + tid] = make_uint2(bits, idx);

  // center-of-mass reduction
  const float v = __uint_as_float(bits);
  const u32 z = idx / 9216u, rem = idx % 9216u, yy = rem / 96u, xw = rem % 96u;
  const float p0 = ((float)z  - 48.f) / 48.f;
  const float p1 = ((float)yy - 48.f) / 48.f;
  const float p2 = ((float)xw - 48.f) / 48.f;

  float sv = v, s0 = p0 * v, s1 = p1 * v, s2 = p2 * v;
  for (int off = 32; off > 0; off >>= 1) {
    sv += __shfl_down(sv, off);
    s0 += __shfl_down(s0, off);
    s1 += __shfl_down(s1, off);
    s2 += __shfl_down(s2, off);
  }
  const int w = tid >> 6, ln = tid & 63;
  if (ln == 0) { rbuf[w][0] = sv; rbuf[w][1] = s0; rbuf[w][2] = s1; rbuf[w][3] = s2; }
  __syncthreads();
  if (tid == 0) {
    float tv = 0.f, t0 = 0.f, t1 = 0.f, t2 = 0.f;
    for (int wv = 0; wv < 8; ++wv) { tv += rbuf[wv][0]; t0 += rbuf[wv][1]; t1 += rbuf[wv][2]; t2 += rbuf[wv][3]; }
    const float dnm = fmaxf(tv, 1e-12f);
    comv[b] = make_float4(t0 / dnm, t1 / dnm, t2 / dnm, 0.f);
  }
}

// ---------------------------------------------------------------------------
// Pass 3: per point: 60-dim features (written to output) + scalar path
// h3 = feat_s[16] @ M[16][128], max-pooled over the 512 points.
// One block per batch, one thread per point.
// ---------------------------------------------------------------------------
__global__ __launch_bounds__(512) void k_features(const uint2* __restrict__ sel,
                                                  const float4* __restrict__ comv,
                                                  const float* __restrict__ M,
                                                  float* __restrict__ dout,
                                                  float* __restrict__ pooled) {
  const int b = blockIdx.x;
  const int t = threadIdx.x;
  __shared__ float fs[NPTS][17];   // +1 pad: avoid 32-way bank conflict on write
  __shared__ float Ms[16 * 128];
  __shared__ float pr[4][128];

  for (int i = t; i < 16 * 128; i += 512) Ms[i] = M[i];

  const uint2 s = sel[(size_t)b * NPTS + t];
  const float v = __uint_as_float(s.x);
  const u32 idx = s.y;
  const u32 z = idx / 9216u, rem = idx % 9216u, yy = rem / 96u, xw = rem % 96u;
  const float4 cm = comv[b];
  const float c0 = ((float)z  - 48.f) / 48.f - cm.x;
  const float c1 = ((float)yy - 48.f) / 48.f - cm.y;
  const float c2 = ((float)xw - 48.f) / 48.f - cm.z;
  const float r = fmaxf(sqrtf(c0 * c0 + c1 * c1 + c2 * c2), 1e-6f);
  const float inv = 1.0f / r;
  const float d0 = c0 * inv, d1 = c1 * inv, d2 = c2 * inv;
  const float v2 = v * v;
  const float rr2 = r * r;
  const float l1 = log1pf(r);
  const float er = expf(-r);
  const float sgv = 1.0f / (1.0f + expf(-v));
  const float sgr = 1.0f / (1.0f + expf(-r));

  float f[60];
  // scalars (16) — these are the only channels feeding the logits path
  f[0]=v;      f[1]=r;      f[2]=C0c;     f[3]=v*r;
  f[4]=v2;     f[5]=l1;     f[6]=sqrtf(v + 1e-6f); f[7]=rr2;
  f[8]=v*C0c;  f[9]=er;     f[10]=v2*v;   f[11]=sqrtf(r);
  f[12]=v*l1;  f[13]=sgv;   f[14]=sgr;    f[15]=v*rr2;
  // vectors (8 x 3)
  f[16]=c0;        f[17]=c1;        f[18]=c2;
  f[19]=c0*v;      f[20]=c1*v;      f[21]=c2*v;
  f[22]=C1c*d0;    f[23]=C1c*d1;    f[24]=C1c*d2;
  f[25]=c0*r;      f[26]=c1*r;      f[27]=c2*r;
  f[28]=d0;        f[29]=d1;        f[30]=d2;
  f[31]=d0*v;      f[32]=d1*v;      f[33]=d2*v;
  f[34]=c0*v2;     f[35]=c1*v2;     f[36]=c2*v2;
  f[37]=C1c*d0*r;  f[38]=C1c*d1*r;  f[39]=C1c*d2*r;
  // tensors (4 x 5)
  const float t0 = C2c * (SQ3c * d0 * d2);
  const float t1 = C2c * (SQ3c * d0 * d1);
  const float t2_ = C2c * (d1 * d1 - 0.5f * (d0 * d0 + d2 * d2));
  const float t3 = C2c * (SQ3c * d1 * d2);
  const float t4 = C2c * (0.5f * SQ3c * (d2 * d2 - d0 * d0));
  f[40]=t0;     f[41]=t1;     f[42]=t2_;     f[43]=t3;     f[44]=t4;
  f[45]=t0*v;   f[46]=t1*v;   f[47]=t2_*v;   f[48]=t3*v;   f[49]=t4*v;
  f[50]=t0*r;   f[51]=t1*r;   f[52]=t2_*r;   f[53]=t3*r;   f[54]=t4*r;
  f[55]=t0*l1;  f[56]=t1*l1;  f[57]=t2_*l1;  f[58]=t3*l1;  f[59]=t4*l1;

  // feat output: d_out[16384 + (b*512 + n)*60 ...]
  float4* ob = reinterpret_cast<float4*>(dout + 16384 + ((size_t)b * NPTS + t) * 60);
  #pragma unroll
  for (int k = 0; k < 15; ++k) ob[k] = make_float4(f[4*k], f[4*k+1], f[4*k+2], f[4*k+3]);

  #pragma unroll
  for (int u = 0; u < 16; ++u) fs[t][u] = f[u];
  __syncthreads();

  // h3 = fs @ Ms, max over points. thread -> (point-group g, channel vv)
  const int g = t >> 7, vv = t & 127;
  float pm = -3.4e38f;
  for (int n = g; n < NPTS; n += 4) {
    float acc = 0.f;
    #pragma unroll
    for (int u = 0; u < 16; ++u) acc += fs[n][u] * Ms[u * 128 + vv];
    pm = fmaxf(pm, acc);
  }
  pr[g][vv] = pm;
  __syncthreads();
  if (g == 0) {
    const float m = fmaxf(fmaxf(pr[0][vv], pr[1][vv]), fmaxf(pr[2][vv], pr[3][vv]));
    pooled[b * 128 + vv] = m;
  }
}

// ---------------------------------------------------------------------------
// Head MLP: logits = relu(pooled @ fc1 + b1) @ fc2 + b2  -> d_out[0:16384]
// ---------------------------------------------------------------------------
__global__ __launch_bounds__(512) void k_head(const float* __restrict__ pooled,
                                              const float* __restrict__ fc1w,
                                              const float* __restrict__ fc1b,
                                              const float* __restrict__ fc2w,
                                              const float* __restrict__ fc2b,
                                              float* __restrict__ dout) {
  const int b = blockIdx.x;
  const int t = threadIdx.x;
  __shared__ float pl[128];
  __shared__ float hid[64];
  if (t < 128) pl[t] = pooled[b * 128 + t];
  __syncthreads();
  if (t < 64) {
    float s = fc1b[t];
    for (int u = 0; u < 128; ++u) s += pl[u] * fc1w[u * 64 + t];
    hid[t] = fmaxf(s, 0.f);
  }
  __syncthreads();
  float s = fc2b[t];
  for (int j = 0; j < 64; ++j) s += hid[j] * fc2w[j * 512 + t];
  dout[b * 512 + t] = s;
}

extern "C" void kernel_launch(void* const* d_in, const int* in_sizes, int n_in,
                              void* d_out, int out_size, void* d_ws, size_t ws_size,
                              hipStream_t stream) {
  const float* x    = (const float*)d_in[0];
  const float* W1   = (const float*)d_in[1];   // W1_0e (16,32)
  const float* W2   = (const float*)d_in[4];   // W2_0e (32,64)
  const float* W3   = (const float*)d_in[7];   // W3_0e (64,128)
  const float* fc1w = (const float*)d_in[8];
  const float* fc1b = (const float*)d_in[9];
  const float* fc2w = (const float*)d_in[10];
  const float* fc2b = (const float*)d_in[11];
  float* out = (float*)d_out;

  // workspace layout (~1.26 MB total)
  uint8_t* ws = (uint8_t*)d_ws;
  int*    cnt    = (int*)ws;                    // 128 B
  float4* comv   = (float4*)(ws + 256);         // 512 B
  float*  pooled = (float*)(ws + 1024);         // 16 KB
  float*  M      = (float*)(ws + 20480);        // 8 KB
  uint2*  sel    = (uint2*)(ws + 32768);        // 128 KB
  uint2*  cand   = (uint2*)(ws + 262144);       // 1 MB

  hipMemsetAsync(cnt, 0, NB * sizeof(int), stream);

  dim3 g1(NVOX / 1024, NB);                     // 256 thr x 4 floats each
  k_collect<<<g1, 256, 0, stream>>>(x, cand, cnt);
  k_buildM<<<1, 128, 0, stream>>>(W1, W2, W3, M);
  k_select<<<NB, 512, 0, stream>>>(x, cand, cnt, sel, comv);
  k_features<<<NB, 512, 0, stream>>>(sel, comv, M, out, pooled);
  k_head<<<NB, 512, 0, stream>>>(pooled, fc1w, fc1b, fc2w, fc2b, out);
}

// Round 2
// 92.618 us; speedup vs baseline: 4.2651x; 4.2651x over previous
//
#include <hip/hip_runtime.h>
#include <hip/hip_bf16.h>
#include <stdint.h>

// Problem constants
#define NVOX   884736      // 96*96*96 voxels per batch
#define NB     32          // batches
#define NPTS   512         // MAX_POINTS
#define CAP    4096        // candidate capacity per batch
#define THRV   0.9990f     // conservative static threshold: E[count]=885/batch
#define BPB    216         // collect blocks per batch (4096 voxels each)
#define LCAP   256         // per-block local candidate capacity (E=4.1, Poisson)
#define CNT_STRIDE 32      // pad each batch counter to its own 128B cacheline

#define C0c  0.28209479177387814f
#define C1c  0.4886025119029199f
#define C2c  0.6307831305050401f
#define SQ3c 1.7320508075688772f

typedef unsigned long long u64;
typedef unsigned int u32;

// ---------------------------------------------------------------------------
// Pass 1: full scan of x. Per-block LDS aggregation of candidates >= THRV,
// ONE global atomic per block to reserve a segment (kills the cacheline
// ping-pong that made the old version 309us). Local overflow forces the
// exact fallback in k_select.
// ---------------------------------------------------------------------------
__global__ __launch_bounds__(256) void k_collect(const float* __restrict__ x,
                                                 uint2* __restrict__ cand,
                                                 int* __restrict__ cnt) {
  const int b = blockIdx.y;
  __shared__ uint2 lbuf[LCAP];
  __shared__ int lcnt;
  __shared__ int gbase;
  if (threadIdx.x == 0) lcnt = 0;
  __syncthreads();

  const float4* xb = reinterpret_cast<const float4*>(x + (size_t)b * NVOX);
  const int t0 = blockIdx.x * 1024 + threadIdx.x;   // float4 index
  float4 q[4];
  #pragma unroll
  for (int it = 0; it < 4; ++it) q[it] = xb[t0 + it * 256];

  #pragma unroll
  for (int it = 0; it < 4; ++it) {
    const float4 qq = q[it];
    const u32 base = (u32)(t0 + it * 256) * 4u;
    if (qq.x >= THRV) { int p = atomicAdd(&lcnt, 1); if (p < LCAP) lbuf[p] = make_uint2(__float_as_uint(qq.x), base      ); }
    if (qq.y >= THRV) { int p = atomicAdd(&lcnt, 1); if (p < LCAP) lbuf[p] = make_uint2(__float_as_uint(qq.y), base + 1u); }
    if (qq.z >= THRV) { int p = atomicAdd(&lcnt, 1); if (p < LCAP) lbuf[p] = make_uint2(__float_as_uint(qq.z), base + 2u); }
    if (qq.w >= THRV) { int p = atomicAdd(&lcnt, 1); if (p < LCAP) lbuf[p] = make_uint2(__float_as_uint(qq.w), base + 3u); }
  }
  __syncthreads();

  if (threadIdx.x == 0) {
    int n = lcnt;
    if (n > LCAP) {
      gbase = atomicAdd(&cnt[b * CNT_STRIDE], LCAP);
      atomicAdd(&cnt[b * CNT_STRIDE], CAP + 1);     // force fallback path
    } else {
      gbase = (n > 0) ? atomicAdd(&cnt[b * CNT_STRIDE], n) : 0;
    }
  }
  __syncthreads();

  const int n = lcnt < LCAP ? lcnt : LCAP;
  for (int i = threadIdx.x; i < n; i += 256) {
    const int p = gbase + i;
    if (p < CAP) cand[(size_t)b * CAP + p] = lbuf[i];
  }
}

// ---------------------------------------------------------------------------
// Pass 2: per batch, exact top-512 by rank over packed keys (bits<<32)|~idx
// (encodes jax.lax.top_k order: value desc, index asc on ties).
// Fallback (static-threshold under/overflow — never occurs for this input):
// exact fine histogram near 1.0 + re-collect. Also computes center-of-mass.
// ---------------------------------------------------------------------------
__global__ __launch_bounds__(512) void k_select(const float* __restrict__ x,
                                                const uint2* __restrict__ cand,
                                                const int* __restrict__ cnt,
                                                uint2* __restrict__ sel,
                                                float4* __restrict__ comv) {
  const int b = blockIdx.x;
  const int tid = threadIdx.x;
  __shared__ u64 lk[CAP];          // 32 KB (reused as histogram in fallback)
  __shared__ u64 sk[NPTS];
  __shared__ float rbuf[8][4];
  __shared__ int sC;
  __shared__ u32 sthr;

  int C = cnt[b * CNT_STRIDE];
  if (C >= NPTS && C <= CAP) {
    for (int i = tid; i < C; i += 512) {
      const uint2 cd = cand[(size_t)b * CAP + i];
      lk[i] = ((u64)cd.x << 32) | (u64)(~cd.y);
    }
  } else {
    // ---- fallback: exact threshold via 4096-bin histogram near 1.0
    u32* hist = reinterpret_cast<u32*>(lk);
    for (int i = tid; i < 4096; i += 512) hist[i] = 0u;
    __syncthreads();
    const u32* xb = reinterpret_cast<const u32*>(x) + (size_t)b * NVOX;
    for (int i = tid; i < NVOX; i += 512) {
      const u32 bits = xb[i];
      u32 key;
      if (bits >= 0x3F800000u) key = 0u;
      else { const u32 dd = 0x3F7FFFFFu - bits; key = dd >> 8; if (key > 4095u) key = 4095u; }
      atomicAdd(&hist[key], 1u);
    }
    __syncthreads();
    if (tid == 0) {
      u32 cum = 0; int kt = 4095;
      for (int k = 0; k < 4096; ++k) { cum += hist[k]; if (cum >= (u32)NPTS) { kt = k; break; } }
      sthr = (kt >= 4095) ? 0u : (0x3F800000u - ((u32)(kt + 1) << 8));
      sC = 0;
    }
    __syncthreads();
    const u32 thr = sthr;
    for (int i = tid; i < NVOX; i += 512) {
      const u32 bits = xb[i];
      if (bits >= thr) {
        const int p = atomicAdd(&sC, 1);
        if (p < CAP) lk[p] = ((u64)bits << 32) | (u64)(~(u32)i);
      }
    }
    __syncthreads();
    C = sC < CAP ? sC : CAP;
  }
  __syncthreads();

  // exact rank of each candidate (keys unique: idx unique)
  for (int i = tid; i < C; i += 512) {
    const u64 ki = lk[i];
    int rank = 0;
    for (int j = 0; j < C; ++j) rank += (lk[j] > ki) ? 1 : 0;
    if (rank < NPTS) sk[rank] = ki;
  }
  __syncthreads();

  const u64 key = sk[tid];
  const u32 bits = (u32)(key >> 32);
  const u32 idx = ~((u32)key);
  sel[(size_t)b * NPTS + tid] = make_uint2(bits, idx);

  // center-of-mass reduction
  const float v = __uint_as_float(bits);
  const u32 z = idx / 9216u, rem = idx % 9216u, yy = rem / 96u, xw = rem % 96u;
  const float p0 = ((float)z  - 48.f) / 48.f;
  const float p1 = ((float)yy - 48.f) / 48.f;
  const float p2 = ((float)xw - 48.f) / 48.f;

  float sv = v, s0 = p0 * v, s1 = p1 * v, s2 = p2 * v;
  for (int off = 32; off > 0; off >>= 1) {
    sv += __shfl_down(sv, off);
    s0 += __shfl_down(s0, off);
    s1 += __shfl_down(s1, off);
    s2 += __shfl_down(s2, off);
  }
  const int w = tid >> 6, ln = tid & 63;
  if (ln == 0) { rbuf[w][0] = sv; rbuf[w][1] = s0; rbuf[w][2] = s1; rbuf[w][3] = s2; }
  __syncthreads();
  if (tid == 0) {
    float tv = 0.f, t0 = 0.f, t1 = 0.f, t2 = 0.f;
    for (int wv = 0; wv < 8; ++wv) { tv += rbuf[wv][0]; t0 += rbuf[wv][1]; t1 += rbuf[wv][2]; t2 += rbuf[wv][3]; }
    const float dnm = fmaxf(tv, 1e-12f);
    comv[b] = make_float4(t0 / dnm, t1 / dnm, t2 / dnm, 0.f);
  }
}

// ---------------------------------------------------------------------------
// Pass 3 (fused): per point 60-dim features (-> output), collapsed scalar
// matrix M (built in-block from W1/W2/W3), h3 = feat_s @ M max-pooled,
// then the head MLP -> logits. One block per batch.
// ---------------------------------------------------------------------------
__global__ __launch_bounds__(512) void k_features(const uint2* __restrict__ sel,
                                                  const float4* __restrict__ comv,
                                                  const float* __restrict__ W1,
                                                  const float* __restrict__ W2,
                                                  const float* __restrict__ W3,
                                                  const float* __restrict__ fc1w,
                                                  const float* __restrict__ fc1b,
                                                  const float* __restrict__ fc2w,
                                                  const float* __restrict__ fc2b,
                                                  float* __restrict__ dout) {
  const int b = blockIdx.x;
  const int t = threadIdx.x;
  __shared__ float fs[NPTS][17];   // +1 pad: avoid bank conflicts
  __shared__ float Tm[16 * 64];
  __shared__ float Ms[16 * 128];
  __shared__ float pr[4][128];
  __shared__ float pl[128];
  __shared__ float hid[64];

  // --- collapsed scalar-path matrix M = (W1_0e/4)(W2_0e/sqrt32)(W3_0e/8)
  const float s1 = 1.0f / (4.0f * sqrtf(32.0f));
  for (int e = t; e < 16 * 64; e += 512) {
    const int u = e >> 6, j = e & 63;
    float s = 0.f;
    for (int k = 0; k < 32; ++k) s += W1[u * 32 + k] * W2[k * 64 + j];
    Tm[e] = s * s1;
  }
  __syncthreads();
  for (int e = t; e < 16 * 128; e += 512) {
    const int u = e >> 7, v = e & 127;
    float s = 0.f;
    for (int j = 0; j < 64; ++j) s += Tm[u * 64 + j] * W3[j * 128 + v];
    Ms[e] = s * 0.125f;
  }

  // --- per-point features
  const uint2 s = sel[(size_t)b * NPTS + t];
  const float v = __uint_as_float(s.x);
  const u32 idx = s.y;
  const u32 z = idx / 9216u, rem = idx % 9216u, yy = rem / 96u, xw = rem % 96u;
  const float4 cm = comv[b];
  const float c0 = ((float)z  - 48.f) / 48.f - cm.x;
  const float c1 = ((float)yy - 48.f) / 48.f - cm.y;
  const float c2 = ((float)xw - 48.f) / 48.f - cm.z;
  const float r = fmaxf(sqrtf(c0 * c0 + c1 * c1 + c2 * c2), 1e-6f);
  const float inv = 1.0f / r;
  const float d0 = c0 * inv, d1 = c1 * inv, d2 = c2 * inv;
  const float v2 = v * v;
  const float rr2 = r * r;
  const float l1 = log1pf(r);
  const float er = expf(-r);
  const float sgv = 1.0f / (1.0f + expf(-v));
  const float sgr = 1.0f / (1.0f + expf(-r));

  float f[60];
  f[0]=v;      f[1]=r;      f[2]=C0c;     f[3]=v*r;
  f[4]=v2;     f[5]=l1;     f[6]=sqrtf(v + 1e-6f); f[7]=rr2;
  f[8]=v*C0c;  f[9]=er;     f[10]=v2*v;   f[11]=sqrtf(r);
  f[12]=v*l1;  f[13]=sgv;   f[14]=sgr;    f[15]=v*rr2;
  f[16]=c0;        f[17]=c1;        f[18]=c2;
  f[19]=c0*v;      f[20]=c1*v;      f[21]=c2*v;
  f[22]=C1c*d0;    f[23]=C1c*d1;    f[24]=C1c*d2;
  f[25]=c0*r;      f[26]=c1*r;      f[27]=c2*r;
  f[28]=d0;        f[29]=d1;        f[30]=d2;
  f[31]=d0*v;      f[32]=d1*v;      f[33]=d2*v;
  f[34]=c0*v2;     f[35]=c1*v2;     f[36]=c2*v2;
  f[37]=C1c*d0*r;  f[38]=C1c*d1*r;  f[39]=C1c*d2*r;
  const float t0 = C2c * (SQ3c * d0 * d2);
  const float t1 = C2c * (SQ3c * d0 * d1);
  const float t2_ = C2c * (d1 * d1 - 0.5f * (d0 * d0 + d2 * d2));
  const float t3 = C2c * (SQ3c * d1 * d2);
  const float t4 = C2c * (0.5f * SQ3c * (d2 * d2 - d0 * d0));
  f[40]=t0;     f[41]=t1;     f[42]=t2_;     f[43]=t3;     f[44]=t4;
  f[45]=t0*v;   f[46]=t1*v;   f[47]=t2_*v;   f[48]=t3*v;   f[49]=t4*v;
  f[50]=t0*r;   f[51]=t1*r;   f[52]=t2_*r;   f[53]=t3*r;   f[54]=t4*r;
  f[55]=t0*l1;  f[56]=t1*l1;  f[57]=t2_*l1;  f[58]=t3*l1;  f[59]=t4*l1;

  // feat output: d_out[16384 + (b*512 + n)*60 ...]
  float4* ob = reinterpret_cast<float4*>(dout + 16384 + ((size_t)b * NPTS + t) * 60);
  #pragma unroll
  for (int k = 0; k < 15; ++k) ob[k] = make_float4(f[4*k], f[4*k+1], f[4*k+2], f[4*k+3]);

  #pragma unroll
  for (int u = 0; u < 16; ++u) fs[t][u] = f[u];
  __syncthreads();

  // --- h3 = fs @ Ms, max over points
  const int g = t >> 7, vv = t & 127;
  float pm = -3.4e38f;
  for (int n = g; n < NPTS; n += 4) {
    float acc = 0.f;
    #pragma unroll
    for (int u = 0; u < 16; ++u) acc += fs[n][u] * Ms[u * 128 + vv];
    pm = fmaxf(pm, acc);
  }
  pr[g][vv] = pm;
  __syncthreads();
  if (g == 0) pl[vv] = fmaxf(fmaxf(pr[0][vv], pr[1][vv]), fmaxf(pr[2][vv], pr[3][vv]));
  __syncthreads();

  // --- head MLP
  if (t < 64) {
    float sh = fc1b[t];
    for (int u = 0; u < 128; ++u) sh += pl[u] * fc1w[u * 64 + t];
    hid[t] = fmaxf(sh, 0.f);
  }
  __syncthreads();
  float sl = fc2b[t];
  for (int j = 0; j < 64; ++j) sl += hid[j] * fc2w[j * 512 + t];
  dout[b * 512 + t] = sl;
}

extern "C" void kernel_launch(void* const* d_in, const int* in_sizes, int n_in,
                              void* d_out, int out_size, void* d_ws, size_t ws_size,
                              hipStream_t stream) {
  const float* x    = (const float*)d_in[0];
  const float* W1   = (const float*)d_in[1];   // W1_0e (16,32)
  const float* W2   = (const float*)d_in[4];   // W2_0e (32,64)
  const float* W3   = (const float*)d_in[7];   // W3_0e (64,128)
  const float* fc1w = (const float*)d_in[8];
  const float* fc1b = (const float*)d_in[9];
  const float* fc2w = (const float*)d_in[10];
  const float* fc2b = (const float*)d_in[11];
  float* out = (float*)d_out;

  // workspace layout
  uint8_t* ws = (uint8_t*)d_ws;
  int*    cnt  = (int*)ws;                      // 4 KB (32 x 128B-padded)
  float4* comv = (float4*)(ws + 4096);          // 512 B
  uint2*  sel  = (uint2*)(ws + 8192);           // 128 KB
  uint2*  cand = (uint2*)(ws + 8192 + 131072);  // 1 MB

  hipMemsetAsync(cnt, 0, NB * CNT_STRIDE * sizeof(int), stream);

  dim3 g1(BPB, NB);
  k_collect<<<g1, 256, 0, stream>>>(x, cand, cnt);
  k_select<<<NB, 512, 0, stream>>>(x, cand, cnt, sel, comv);
  k_features<<<NB, 512, 0, stream>>>(sel, comv, W1, W2, W3, fc1w, fc1b, fc2w, fc2b, out);
}

// Round 3
// 91.550 us; speedup vs baseline: 4.3148x; 1.0117x over previous
//
#include <hip/hip_runtime.h>
#include <hip/hip_bf16.h>
#include <stdint.h>

// Problem constants
#define NVOX   884736      // 96*96*96 voxels per batch
#define NB     32          // batches
#define NPTS   512         // MAX_POINTS
#define CAP    4096        // candidate capacity per batch
#define THRV   0.9990f     // conservative static threshold: E[count]=885/batch
#define BPB    216         // collect blocks per batch (4096 voxels each)
#define LCAP   256         // per-block local candidate capacity (E=4.1, Poisson)
#define CNT_STRIDE 32      // pad each batch counter to its own 128B cacheline

#define C0c  0.28209479177387814f
#define C1c  0.4886025119029199f
#define C2c  0.6307831305050401f
#define SQ3c 1.7320508075688772f

typedef unsigned long long u64;
typedef unsigned int u32;

// ---------------------------------------------------------------------------
// Zero the per-batch counters. A dedicated tiny kernel: hipMemsetAsync's
// fillBufferAligned node cost 65.8us per graph replay (rocprof round 2) for a
// 4KB fill; a plain kernel node is ~2us.
// ---------------------------------------------------------------------------
__global__ __launch_bounds__(256) void k_zero(int* __restrict__ cnt) {
  const int t = threadIdx.x;
  for (int i = t; i < NB * CNT_STRIDE; i += 256) cnt[i] = 0;
}

// ---------------------------------------------------------------------------
// Pass 1: full scan of x. Per-block LDS aggregation of candidates >= THRV,
// ONE global atomic per block to reserve a segment. Local overflow forces
// the exact fallback in k_select.
// ---------------------------------------------------------------------------
__global__ __launch_bounds__(256) void k_collect(const float* __restrict__ x,
                                                 uint2* __restrict__ cand,
                                                 int* __restrict__ cnt) {
  const int b = blockIdx.y;
  __shared__ uint2 lbuf[LCAP];
  __shared__ int lcnt;
  __shared__ int gbase;
  if (threadIdx.x == 0) lcnt = 0;
  __syncthreads();

  const float4* xb = reinterpret_cast<const float4*>(x + (size_t)b * NVOX);
  const int t0 = blockIdx.x * 1024 + threadIdx.x;   // float4 index
  float4 q[4];
  #pragma unroll
  for (int it = 0; it < 4; ++it) q[it] = xb[t0 + it * 256];

  #pragma unroll
  for (int it = 0; it < 4; ++it) {
    const float4 qq = q[it];
    const u32 base = (u32)(t0 + it * 256) * 4u;
    if (qq.x >= THRV) { int p = atomicAdd(&lcnt, 1); if (p < LCAP) lbuf[p] = make_uint2(__float_as_uint(qq.x), base      ); }
    if (qq.y >= THRV) { int p = atomicAdd(&lcnt, 1); if (p < LCAP) lbuf[p] = make_uint2(__float_as_uint(qq.y), base + 1u); }
    if (qq.z >= THRV) { int p = atomicAdd(&lcnt, 1); if (p < LCAP) lbuf[p] = make_uint2(__float_as_uint(qq.z), base + 2u); }
    if (qq.w >= THRV) { int p = atomicAdd(&lcnt, 1); if (p < LCAP) lbuf[p] = make_uint2(__float_as_uint(qq.w), base + 3u); }
  }
  __syncthreads();

  if (threadIdx.x == 0) {
    int n = lcnt;
    if (n > LCAP) {
      gbase = atomicAdd(&cnt[b * CNT_STRIDE], LCAP);
      atomicAdd(&cnt[b * CNT_STRIDE], CAP + 1);     // force fallback path
    } else {
      gbase = (n > 0) ? atomicAdd(&cnt[b * CNT_STRIDE], n) : 0;
    }
  }
  __syncthreads();

  const int n = lcnt < LCAP ? lcnt : LCAP;
  for (int i = threadIdx.x; i < n; i += 256) {
    const int p = gbase + i;
    if (p < CAP) cand[(size_t)b * CAP + p] = lbuf[i];
  }
}

// ---------------------------------------------------------------------------
// Pass 2: per batch, exact top-512 by rank over packed keys (bits<<32)|~idx
// (encodes jax.lax.top_k order: value desc, index asc on ties).
// Fallback (static-threshold under/overflow — never occurs for this input):
// exact fine histogram near 1.0 + re-collect. Also computes center-of-mass.
// ---------------------------------------------------------------------------
__global__ __launch_bounds__(512) void k_select(const float* __restrict__ x,
                                                const uint2* __restrict__ cand,
                                                const int* __restrict__ cnt,
                                                uint2* __restrict__ sel,
                                                float4* __restrict__ comv) {
  const int b = blockIdx.x;
  const int tid = threadIdx.x;
  __shared__ u64 lk[CAP];          // 32 KB (reused as histogram in fallback)
  __shared__ u64 sk[NPTS];
  __shared__ float rbuf[8][4];
  __shared__ int sC;
  __shared__ u32 sthr;

  int C = cnt[b * CNT_STRIDE];
  if (C >= NPTS && C <= CAP) {
    for (int i = tid; i < C; i += 512) {
      const uint2 cd = cand[(size_t)b * CAP + i];
      lk[i] = ((u64)cd.x << 32) | (u64)(~cd.y);
    }
  } else {
    // ---- fallback: exact threshold via 4096-bin histogram near 1.0
    u32* hist = reinterpret_cast<u32*>(lk);
    for (int i = tid; i < 4096; i += 512) hist[i] = 0u;
    __syncthreads();
    const u32* xb = reinterpret_cast<const u32*>(x) + (size_t)b * NVOX;
    for (int i = tid; i < NVOX; i += 512) {
      const u32 bits = xb[i];
      u32 key;
      if (bits >= 0x3F800000u) key = 0u;
      else { const u32 dd = 0x3F7FFFFFu - bits; key = dd >> 8; if (key > 4095u) key = 4095u; }
      atomicAdd(&hist[key], 1u);
    }
    __syncthreads();
    if (tid == 0) {
      u32 cum = 0; int kt = 4095;
      for (int k = 0; k < 4096; ++k) { cum += hist[k]; if (cum >= (u32)NPTS) { kt = k; break; } }
      sthr = (kt >= 4095) ? 0u : (0x3F800000u - ((u32)(kt + 1) << 8));
      sC = 0;
    }
    __syncthreads();
    const u32 thr = sthr;
    for (int i = tid; i < NVOX; i += 512) {
      const u32 bits = xb[i];
      if (bits >= thr) {
        const int p = atomicAdd(&sC, 1);
        if (p < CAP) lk[p] = ((u64)bits << 32) | (u64)(~(u32)i);
      }
    }
    __syncthreads();
    C = sC < CAP ? sC : CAP;
  }
  __syncthreads();

  // exact rank of each candidate (keys unique: idx unique)
  for (int i = tid; i < C; i += 512) {
    const u64 ki = lk[i];
    int rank = 0;
    for (int j = 0; j < C; ++j) rank += (lk[j] > ki) ? 1 : 0;
    if (rank < NPTS) sk[rank] = ki;
  }
  __syncthreads();

  const u64 key = sk[tid];
  const u32 bits = (u32)(key >> 32);
  const u32 idx = ~((u32)key);
  sel[(size_t)b * NPTS + tid] = make_uint2(bits, idx);

  // center-of-mass reduction
  const float v = __uint_as_float(bits);
  const u32 z = idx / 9216u, rem = idx % 9216u, yy = rem / 96u, xw = rem % 96u;
  const float p0 = ((float)z  - 48.f) / 48.f;
  const float p1 = ((float)yy - 48.f) / 48.f;
  const float p2 = ((float)xw - 48.f) / 48.f;

  float sv = v, s0 = p0 * v, s1 = p1 * v, s2 = p2 * v;
  for (int off = 32; off > 0; off >>= 1) {
    sv += __shfl_down(sv, off);
    s0 += __shfl_down(s0, off);
    s1 += __shfl_down(s1, off);
    s2 += __shfl_down(s2, off);
  }
  const int w = tid >> 6, ln = tid & 63;
  if (ln == 0) { rbuf[w][0] = sv; rbuf[w][1] = s0; rbuf[w][2] = s1; rbuf[w][3] = s2; }
  __syncthreads();
  if (tid == 0) {
    float tv = 0.f, t0 = 0.f, t1 = 0.f, t2 = 0.f;
    for (int wv = 0; wv < 8; ++wv) { tv += rbuf[wv][0]; t0 += rbuf[wv][1]; t1 += rbuf[wv][2]; t2 += rbuf[wv][3]; }
    const float dnm = fmaxf(tv, 1e-12f);
    comv[b] = make_float4(t0 / dnm, t1 / dnm, t2 / dnm, 0.f);
  }
}

// ---------------------------------------------------------------------------
// Pass 3 (fused): per point 60-dim features (-> output), collapsed scalar
// matrix M (built in-block from W1/W2/W3), h3 = feat_s @ M max-pooled,
// then the head MLP -> logits. One block per batch.
// ---------------------------------------------------------------------------
__global__ __launch_bounds__(512) void k_features(const uint2* __restrict__ sel,
                                                  const float4* __restrict__ comv,
                                                  const float* __restrict__ W1,
                                                  const float* __restrict__ W2,
                                                  const float* __restrict__ W3,
                                                  const float* __restrict__ fc1w,
                                                  const float* __restrict__ fc1b,
                                                  const float* __restrict__ fc2w,
                                                  const float* __restrict__ fc2b,
                                                  float* __restrict__ dout) {
  const int b = blockIdx.x;
  const int t = threadIdx.x;
  __shared__ float fs[NPTS][17];   // +1 pad: avoid bank conflicts
  __shared__ float Tm[16 * 64];
  __shared__ float Ms[16 * 128];
  __shared__ float pr[4][128];
  __shared__ float pl[128];
  __shared__ float hid[64];

  // --- collapsed scalar-path matrix M = (W1_0e/4)(W2_0e/sqrt32)(W3_0e/8)
  const float s1 = 1.0f / (4.0f * sqrtf(32.0f));
  for (int e = t; e < 16 * 64; e += 512) {
    const int u = e >> 6, j = e & 63;
    float s = 0.f;
    for (int k = 0; k < 32; ++k) s += W1[u * 32 + k] * W2[k * 64 + j];
    Tm[e] = s * s1;
  }
  __syncthreads();
  for (int e = t; e < 16 * 128; e += 512) {
    const int u = e >> 7, v = e & 127;
    float s = 0.f;
    for (int j = 0; j < 64; ++j) s += Tm[u * 64 + j] * W3[j * 128 + v];
    Ms[e] = s * 0.125f;
  }

  // --- per-point features
  const uint2 s = sel[(size_t)b * NPTS + t];
  const float v = __uint_as_float(s.x);
  const u32 idx = s.y;
  const u32 z = idx / 9216u, rem = idx % 9216u, yy = rem / 96u, xw = rem % 96u;
  const float4 cm = comv[b];
  const float c0 = ((float)z  - 48.f) / 48.f - cm.x;
  const float c1 = ((float)yy - 48.f) / 48.f - cm.y;
  const float c2 = ((float)xw - 48.f) / 48.f - cm.z;
  const float r = fmaxf(sqrtf(c0 * c0 + c1 * c1 + c2 * c2), 1e-6f);
  const float inv = 1.0f / r;
  const float d0 = c0 * inv, d1 = c1 * inv, d2 = c2 * inv;
  const float v2 = v * v;
  const float rr2 = r * r;
  const float l1 = log1pf(r);
  const float er = expf(-r);
  const float sgv = 1.0f / (1.0f + expf(-v));
  const float sgr = 1.0f / (1.0f + expf(-r));

  float f[60];
  f[0]=v;      f[1]=r;      f[2]=C0c;     f[3]=v*r;
  f[4]=v2;     f[5]=l1;     f[6]=sqrtf(v + 1e-6f); f[7]=rr2;
  f[8]=v*C0c;  f[9]=er;     f[10]=v2*v;   f[11]=sqrtf(r);
  f[12]=v*l1;  f[13]=sgv;   f[14]=sgr;    f[15]=v*rr2;
  f[16]=c0;        f[17]=c1;        f[18]=c2;
  f[19]=c0*v;      f[20]=c1*v;      f[21]=c2*v;
  f[22]=C1c*d0;    f[23]=C1c*d1;    f[24]=C1c*d2;
  f[25]=c0*r;      f[26]=c1*r;      f[27]=c2*r;
  f[28]=d0;        f[29]=d1;        f[30]=d2;
  f[31]=d0*v;      f[32]=d1*v;      f[33]=d2*v;
  f[34]=c0*v2;     f[35]=c1*v2;     f[36]=c2*v2;
  f[37]=C1c*d0*r;  f[38]=C1c*d1*r;  f[39]=C1c*d2*r;
  const float t0 = C2c * (SQ3c * d0 * d2);
  const float t1 = C2c * (SQ3c * d0 * d1);
  const float t2_ = C2c * (d1 * d1 - 0.5f * (d0 * d0 + d2 * d2));
  const float t3 = C2c * (SQ3c * d1 * d2);
  const float t4 = C2c * (0.5f * SQ3c * (d2 * d2 - d0 * d0));
  f[40]=t0;     f[41]=t1;     f[42]=t2_;     f[43]=t3;     f[44]=t4;
  f[45]=t0*v;   f[46]=t1*v;   f[47]=t2_*v;   f[48]=t3*v;   f[49]=t4*v;
  f[50]=t0*r;   f[51]=t1*r;   f[52]=t2_*r;   f[53]=t3*r;   f[54]=t4*r;
  f[55]=t0*l1;  f[56]=t1*l1;  f[57]=t2_*l1;  f[58]=t3*l1;  f[59]=t4*l1;

  // feat output: d_out[16384 + (b*512 + n)*60 ...]
  float4* ob = reinterpret_cast<float4*>(dout + 16384 + ((size_t)b * NPTS + t) * 60);
  #pragma unroll
  for (int k = 0; k < 15; ++k) ob[k] = make_float4(f[4*k], f[4*k+1], f[4*k+2], f[4*k+3]);

  #pragma unroll
  for (int u = 0; u < 16; ++u) fs[t][u] = f[u];
  __syncthreads();

  // --- h3 = fs @ Ms, max over points
  const int g = t >> 7, vv = t & 127;
  float pm = -3.4e38f;
  for (int n = g; n < NPTS; n += 4) {
    float acc = 0.f;
    #pragma unroll
    for (int u = 0; u < 16; ++u) acc += fs[n][u] * Ms[u * 128 + vv];
    pm = fmaxf(pm, acc);
  }
  pr[g][vv] = pm;
  __syncthreads();
  if (g == 0) pl[vv] = fmaxf(fmaxf(pr[0][vv], pr[1][vv]), fmaxf(pr[2][vv], pr[3][vv]));
  __syncthreads();

  // --- head MLP
  if (t < 64) {
    float sh = fc1b[t];
    for (int u = 0; u < 128; ++u) sh += pl[u] * fc1w[u * 64 + t];
    hid[t] = fmaxf(sh, 0.f);
  }
  __syncthreads();
  float sl = fc2b[t];
  for (int j = 0; j < 64; ++j) sl += hid[j] * fc2w[j * 512 + t];
  dout[b * 512 + t] = sl;
}

extern "C" void kernel_launch(void* const* d_in, const int* in_sizes, int n_in,
                              void* d_out, int out_size, void* d_ws, size_t ws_size,
                              hipStream_t stream) {
  const float* x    = (const float*)d_in[0];
  const float* W1   = (const float*)d_in[1];   // W1_0e (16,32)
  const float* W2   = (const float*)d_in[4];   // W2_0e (32,64)
  const float* W3   = (const float*)d_in[7];   // W3_0e (64,128)
  const float* fc1w = (const float*)d_in[8];
  const float* fc1b = (const float*)d_in[9];
  const float* fc2w = (const float*)d_in[10];
  const float* fc2b = (const float*)d_in[11];
  float* out = (float*)d_out;

  // workspace layout
  uint8_t* ws = (uint8_t*)d_ws;
  int*    cnt  = (int*)ws;                      // 4 KB (32 x 128B-padded)
  float4* comv = (float4*)(ws + 4096);          // 512 B
  uint2*  sel  = (uint2*)(ws + 8192);           // 128 KB
  uint2*  cand = (uint2*)(ws + 8192 + 131072);  // 1 MB

  k_zero<<<1, 256, 0, stream>>>(cnt);
  dim3 g1(BPB, NB);
  k_collect<<<g1, 256, 0, stream>>>(x, cand, cnt);
  k_select<<<NB, 512, 0, stream>>>(x, cand, cnt, sel, comv);
  k_features<<<NB, 512, 0, stream>>>(sel, comv, W1, W2, W3, fc1w, fc1b, fc2w, fc2b, out);
}

// Round 6
// 85.174 us; speedup vs baseline: 4.6378x; 1.0749x over previous
//
#include <hip/hip_runtime.h>
#include <hip/hip_bf16.h>
#include <stdint.h>

// Problem constants
#define NVOX   884736      // 96*96*96 voxels per batch
#define NB     32          // batches
#define NPTS   512         // MAX_POINTS
#define CAP    4096        // worker candidate capacity per batch
#define THRV   0.9990f     // static threshold: E[count]=885/batch
#define BPB    216         // collect blocks per batch (4096 voxels each)
#define SLOT   64          // per-block candidate slots (lambda=4.1, P(>63) astronomically small)
#define LBUF   80          // LDS staging capacity

#define C0c  0.28209479177387814f
#define C1c  0.4886025119029199f
#define C2c  0.6307831305050401f
#define SQ3c 1.7320508075688772f

typedef unsigned long long u64;
typedef unsigned int u32;

// ---------------------------------------------------------------------------
// Node 1: full scan of x. Each block scans 4096 voxels and writes candidates
// >= THRV into its FIXED slot region (plain stores, zero global atomics,
// nothing needs pre-zeroing). Cross-block visibility is provided by the
// kernel-node boundary (the intra-kernel election of R4/R5 was not reliable
// across XCDs; node boundaries are — R1-R3 all passed with them).
// ---------------------------------------------------------------------------
__global__ __launch_bounds__(256) void k_collect(const float* __restrict__ x,
                                                 u64* __restrict__ cand,
                                                 u32* __restrict__ counts) {
  const int b   = blockIdx.y;
  const int blk = blockIdx.x;
  const int tid = threadIdx.x;
  __shared__ u64 lbuf[LBUF];
  __shared__ int lcnt;
  if (tid == 0) lcnt = 0;
  __syncthreads();

  const float4* xb = reinterpret_cast<const float4*>(x + (size_t)b * NVOX);
  const int t0 = blk * 1024 + tid;                   // float4 index
  float4 q[4];
  #pragma unroll
  for (int it = 0; it < 4; ++it) q[it] = xb[t0 + it * 256];

  #pragma unroll
  for (int it = 0; it < 4; ++it) {
    const float4 qq = q[it];
    const u32 base = (u32)(t0 + it * 256) * 4u;
    if (qq.x >= THRV) { int p = atomicAdd(&lcnt, 1); if (p < LBUF) lbuf[p] = ((u64)__float_as_uint(qq.x) << 32) | (u64)(~(base      )); }
    if (qq.y >= THRV) { int p = atomicAdd(&lcnt, 1); if (p < LBUF) lbuf[p] = ((u64)__float_as_uint(qq.y) << 32) | (u64)(~(base + 1u)); }
    if (qq.z >= THRV) { int p = atomicAdd(&lcnt, 1); if (p < LBUF) lbuf[p] = ((u64)__float_as_uint(qq.z) << 32) | (u64)(~(base + 2u)); }
    if (qq.w >= THRV) { int p = atomicAdd(&lcnt, 1); if (p < LBUF) lbuf[p] = ((u64)__float_as_uint(qq.w) << 32) | (u64)(~(base + 3u)); }
  }
  __syncthreads();

  const int slot = b * BPB + blk;
  const int n = lcnt;
  const int wn = (n <= SLOT) ? n : SLOT;
  if (tid < wn) cand[(size_t)slot * SLOT + tid] = lbuf[tid];
  if (tid == 0) counts[slot] = (n <= SLOT) ? (u32)n : (u32)(SLOT + 1);  // >SLOT => exact fallback
}

// ---------------------------------------------------------------------------
// Node 2: one block per batch. Gather slots -> exact top-512 rank-select
// (packed keys (bits<<32)|~idx == jax.lax.top_k order) -> COM -> 60-dim
// features (-> output) -> collapsed scalar path + max-pool -> head MLP.
// Exact histogram fallback if the static threshold ever under/overflows.
// ---------------------------------------------------------------------------
__global__ __launch_bounds__(512) void k_worker(const float* __restrict__ x,
                                                const u64* __restrict__ cand,
                                                const u32* __restrict__ counts,
                                                const float* __restrict__ W1,
                                                const float* __restrict__ W2,
                                                const float* __restrict__ W3,
                                                const float* __restrict__ fc1w,
                                                const float* __restrict__ fc1b,
                                                const float* __restrict__ fc2w,
                                                const float* __restrict__ fc2b,
                                                float* __restrict__ dout) {
  const int b   = blockIdx.x;
  const int tid = threadIdx.x;

  // 49152B arena, phase-unioned:
  //  select : lk u64[CAP] @0 (32KB) | cnts u32[216] @32768 | pref u32[216] @33792
  //  feature: fs f32[512][17] @0 (34816B) | Tm @34816 (4KB) | Ms @38912 (8KB) | pr @47104 (2KB)
  __shared__ __align__(16) char smem[49152];
  __shared__ u64 sk[NPTS];
  __shared__ float rbuf[8][4];
  __shared__ float comv[4];
  __shared__ float pl[128];
  __shared__ float hid[64];
  __shared__ int sC;
  __shared__ u32 sthr;

  u64* lk   = reinterpret_cast<u64*>(smem);          // [CAP]
  u32* cnts = reinterpret_cast<u32*>(smem + 32768);  // [BPB]
  u32* pref = reinterpret_cast<u32*>(smem + 33792);  // [BPB]

  for (int i = tid; i < BPB; i += 512) cnts[i] = counts[b * BPB + i];
  __syncthreads();
  if (tid == 0) {
    int tot = 0, bad = 0;
    for (int i = 0; i < BPB; ++i) { const u32 c = cnts[i]; pref[i] = (u32)tot; if (c > SLOT) bad = 1; tot += (int)c; }
    sC = bad ? -1 : tot;
  }
  __syncthreads();
  int C = sC;

  if (C >= NPTS && C <= CAP) {
    // gather slots into lk[0..C): 2 threads per slot
    const int i = tid >> 1, l2 = tid & 1;
    if (i < BPB) {
      const u32 c = cnts[i], p = pref[i];
      const u64* src = cand + (size_t)(b * BPB + i) * SLOT;
      for (u32 k = (u32)l2; k < c; k += 2) lk[p + k] = src[k];
    }
    __syncthreads();
  } else {
    // ---- exact fallback: fine histogram near 1.0 + re-collect ----
    u32* hist = reinterpret_cast<u32*>(lk);
    for (int i = tid; i < 4096; i += 512) hist[i] = 0u;
    __syncthreads();
    const u32* xb = reinterpret_cast<const u32*>(x) + (size_t)b * NVOX;
    for (int i = tid; i < NVOX; i += 512) {
      const u32 bits = xb[i];
      u32 key;
      if (bits >= 0x3F800000u) key = 0u;
      else { const u32 dd = 0x3F7FFFFFu - bits; key = dd >> 8; if (key > 4095u) key = 4095u; }
      atomicAdd(&hist[key], 1u);
    }
    __syncthreads();
    if (tid == 0) {
      u32 cum = 0; int kt = 4095;
      for (int k = 0; k < 4096; ++k) { cum += hist[k]; if (cum >= (u32)NPTS) { kt = k; break; } }
      sthr = (kt >= 4095) ? 0u : (0x3F800000u - ((u32)(kt + 1) << 8));
      sC = 0;
    }
    __syncthreads();
    const u32 thr = sthr;
    for (int i = tid; i < NVOX; i += 512) {
      const u32 bits = xb[i];
      if (bits >= thr) {
        const int p = atomicAdd(&sC, 1);
        if (p < CAP) lk[p] = ((u64)bits << 32) | (u64)(~(u32)i);
      }
    }
    __syncthreads();
    C = sC < CAP ? sC : CAP;
    __syncthreads();
  }

  // ---- exact rank-select (keys unique) into sk[0..NPTS) ----
  for (int i = tid; i < C; i += 512) {
    const u64 ki = lk[i];
    int rank = 0;
    for (int j = 0; j < C; ++j) rank += (lk[j] > ki) ? 1 : 0;
    if (rank < NPTS) sk[rank] = ki;
  }
  __syncthreads();

  const u64 key = sk[tid];
  const u32 bits = (u32)(key >> 32);
  const u32 idx  = ~((u32)key);
  const float v  = __uint_as_float(bits);
  const u32 z = idx / 9216u, rem = idx % 9216u, yy = rem / 96u, xw = rem % 96u;
  const float p0 = ((float)z  - 48.f) / 48.f;
  const float p1 = ((float)yy - 48.f) / 48.f;
  const float p2 = ((float)xw - 48.f) / 48.f;

  // ---- center of mass ----
  {
    float sv = v, s0 = p0 * v, s1 = p1 * v, s2 = p2 * v;
    for (int off = 32; off > 0; off >>= 1) {
      sv += __shfl_down(sv, off);
      s0 += __shfl_down(s0, off);
      s1 += __shfl_down(s1, off);
      s2 += __shfl_down(s2, off);
    }
    const int w = tid >> 6, ln = tid & 63;
    if (ln == 0) { rbuf[w][0] = sv; rbuf[w][1] = s0; rbuf[w][2] = s1; rbuf[w][3] = s2; }
    __syncthreads();
    if (tid == 0) {
      float tv = 0.f, t0s = 0.f, t1s = 0.f, t2s = 0.f;
      for (int wv = 0; wv < 8; ++wv) { tv += rbuf[wv][0]; t0s += rbuf[wv][1]; t1s += rbuf[wv][2]; t2s += rbuf[wv][3]; }
      const float dnm = fmaxf(tv, 1e-12f);
      comv[0] = t0s / dnm; comv[1] = t1s / dnm; comv[2] = t2s / dnm;
    }
    __syncthreads();
  }

  // ---- features phase (smem re-unioned) ----
  float (*fs)[17] = reinterpret_cast<float(*)[17]>(smem);
  float* Tm = reinterpret_cast<float*>(smem + 34816);
  float* Ms = reinterpret_cast<float*>(smem + 38912);
  float (*pr)[128] = reinterpret_cast<float(*)[128]>(smem + 47104);

  // collapsed scalar-path matrix M = (W1_0e/4)(W2_0e/sqrt32)(W3_0e/8)
  const float s1c = 1.0f / (4.0f * sqrtf(32.0f));
  for (int e = tid; e < 16 * 64; e += 512) {
    const int u = e >> 6, j = e & 63;
    float s = 0.f;
    for (int k = 0; k < 32; ++k) s += W1[u * 32 + k] * W2[k * 64 + j];
    Tm[e] = s * s1c;
  }
  __syncthreads();
  for (int e = tid; e < 16 * 128; e += 512) {
    const int u = e >> 7, vv = e & 127;
    float s = 0.f;
    for (int j = 0; j < 64; ++j) s += Tm[u * 64 + j] * W3[j * 128 + vv];
    Ms[e] = s * 0.125f;
  }

  const float c0 = p0 - comv[0];
  const float c1 = p1 - comv[1];
  const float c2 = p2 - comv[2];
  const float r = fmaxf(sqrtf(c0 * c0 + c1 * c1 + c2 * c2), 1e-6f);
  const float inv = 1.0f / r;
  const float d0 = c0 * inv, d1 = c1 * inv, d2 = c2 * inv;
  const float v2 = v * v;
  const float rr2 = r * r;
  const float l1 = log1pf(r);
  const float er = expf(-r);
  const float sgv = 1.0f / (1.0f + expf(-v));
  const float sgr = 1.0f / (1.0f + expf(-r));

  float f[60];
  f[0]=v;      f[1]=r;      f[2]=C0c;     f[3]=v*r;
  f[4]=v2;     f[5]=l1;     f[6]=sqrtf(v + 1e-6f); f[7]=rr2;
  f[8]=v*C0c;  f[9]=er;     f[10]=v2*v;   f[11]=sqrtf(r);
  f[12]=v*l1;  f[13]=sgv;   f[14]=sgr;    f[15]=v*rr2;
  f[16]=c0;        f[17]=c1;        f[18]=c2;
  f[19]=c0*v;      f[20]=c1*v;      f[21]=c2*v;
  f[22]=C1c*d0;    f[23]=C1c*d1;    f[24]=C1c*d2;
  f[25]=c0*r;      f[26]=c1*r;      f[27]=c2*r;
  f[28]=d0;        f[29]=d1;        f[30]=d2;
  f[31]=d0*v;      f[32]=d1*v;      f[33]=d2*v;
  f[34]=c0*v2;     f[35]=c1*v2;     f[36]=c2*v2;
  f[37]=C1c*d0*r;  f[38]=C1c*d1*r;  f[39]=C1c*d2*r;
  const float t0 = C2c * (SQ3c * d0 * d2);
  const float t1 = C2c * (SQ3c * d0 * d1);
  const float t2_ = C2c * (d1 * d1 - 0.5f * (d0 * d0 + d2 * d2));
  const float t3 = C2c * (SQ3c * d1 * d2);
  const float t4 = C2c * (0.5f * SQ3c * (d2 * d2 - d0 * d0));
  f[40]=t0;     f[41]=t1;     f[42]=t2_;     f[43]=t3;     f[44]=t4;
  f[45]=t0*v;   f[46]=t1*v;   f[47]=t2_*v;   f[48]=t3*v;   f[49]=t4*v;
  f[50]=t0*r;   f[51]=t1*r;   f[52]=t2_*r;   f[53]=t3*r;   f[54]=t4*r;
  f[55]=t0*l1;  f[56]=t1*l1;  f[57]=t2_*l1;  f[58]=t3*l1;  f[59]=t4*l1;

  // feat output: d_out[16384 + (b*512 + n)*60 ...]
  float4* ob = reinterpret_cast<float4*>(dout + 16384 + ((size_t)b * NPTS + tid) * 60);
  #pragma unroll
  for (int k = 0; k < 15; ++k) ob[k] = make_float4(f[4*k], f[4*k+1], f[4*k+2], f[4*k+3]);

  #pragma unroll
  for (int u = 0; u < 16; ++u) fs[tid][u] = f[u];
  __syncthreads();

  // h3 = fs @ Ms, max over points
  const int g = tid >> 7, vv = tid & 127;
  float mreg[16];
  #pragma unroll
  for (int u = 0; u < 16; ++u) mreg[u] = Ms[u * 128 + vv];
  float pm = -3.4e38f;
  for (int n = g; n < NPTS; n += 4) {
    float acc = 0.f;
    #pragma unroll
    for (int u = 0; u < 16; ++u) acc += fs[n][u] * mreg[u];
    pm = fmaxf(pm, acc);
  }
  pr[g][vv] = pm;
  __syncthreads();
  if (g == 0) pl[vv] = fmaxf(fmaxf(pr[0][vv], pr[1][vv]), fmaxf(pr[2][vv], pr[3][vv]));
  __syncthreads();

  // head MLP
  if (tid < 64) {
    float sh = fc1b[tid];
    for (int u = 0; u < 128; ++u) sh += pl[u] * fc1w[u * 64 + tid];
    hid[tid] = fmaxf(sh, 0.f);
  }
  __syncthreads();
  float sl = fc2b[tid];
  for (int j = 0; j < 64; ++j) sl += hid[j] * fc2w[j * 512 + tid];
  dout[b * 512 + tid] = sl;
}

extern "C" void kernel_launch(void* const* d_in, const int* in_sizes, int n_in,
                              void* d_out, int out_size, void* d_ws, size_t ws_size,
                              hipStream_t stream) {
  const float* x    = (const float*)d_in[0];
  const float* W1   = (const float*)d_in[1];   // W1_0e (16,32)
  const float* W2   = (const float*)d_in[4];   // W2_0e (32,64)
  const float* W3   = (const float*)d_in[7];   // W3_0e (64,128)
  const float* fc1w = (const float*)d_in[8];
  const float* fc1b = (const float*)d_in[9];
  const float* fc2w = (const float*)d_in[10];
  const float* fc2b = (const float*)d_in[11];
  float* out = (float*)d_out;

  // workspace layout (~3.6 MB); every read location is rewritten earlier in
  // the same call -> no cross-replay state, poison-safe.
  uint8_t* ws = (uint8_t*)d_ws;
  u32* counts = (u32*)ws;                       // 6912 u32 (27.6 KB)
  u64* cand   = (u64*)(ws + 32768);             // 6912 * 64 * 8 B = 3.54 MB

  dim3 g(BPB, NB);
  k_collect<<<g, 256, 0, stream>>>(x, cand, counts);
  k_worker<<<NB, 512, 0, stream>>>(x, cand, counts, W1, W2, W3,
                                   fc1w, fc1b, fc2w, fc2b, out);
}

// Round 7
// 45.210 us; speedup vs baseline: 8.7375x; 1.8840x over previous
//
#include <hip/hip_runtime.h>
#include <hip/hip_bf16.h>
#include <stdint.h>

// Problem constants
#define NVOX   884736      // 96*96*96 voxels per batch
#define NB     32          // batches
#define NPTS   512         // MAX_POINTS
#define CAP    4096        // worker candidate capacity per batch
#define THRV   0.9990234375f   // 1 - 2^-10 exactly; bits 0x3F7FC000; E[count]=864/batch (12 sigma > 512)
#define THR_TOP 0x3F7FFFFFu    // largest float bits < 1.0
#define BPB    216         // collect blocks per batch (4096 voxels each)
#define SLOT   64          // per-block candidate slots (lambda=4, P(>64) astronomically small)
#define LBUF   80          // LDS staging capacity
#define NBUCK  128         // rank buckets (128 ulps each over the 16384-ulp threshold range)

#define C0c  0.28209479177387814f
#define C1c  0.4886025119029199f
#define C2c  0.6307831305050401f
#define SQ3c 1.7320508075688772f

typedef unsigned long long u64;
typedef unsigned int u32;

// ---------------------------------------------------------------------------
// Node 1: full scan of x. Each block scans 4096 voxels, writes candidates
// >= THRV into its FIXED slot region (plain stores, zero global atomics,
// nothing pre-zeroed). Cross-block visibility via the kernel-node boundary.
// ---------------------------------------------------------------------------
__global__ __launch_bounds__(256) void k_collect(const float* __restrict__ x,
                                                 u64* __restrict__ cand,
                                                 u32* __restrict__ counts) {
  const int b   = blockIdx.y;
  const int blk = blockIdx.x;
  const int tid = threadIdx.x;
  __shared__ u64 lbuf[LBUF];
  __shared__ int lcnt;
  if (tid == 0) lcnt = 0;
  __syncthreads();

  const float4* xb = reinterpret_cast<const float4*>(x + (size_t)b * NVOX);
  const int t0 = blk * 1024 + tid;                   // float4 index
  float4 q[4];
  #pragma unroll
  for (int it = 0; it < 4; ++it) q[it] = xb[t0 + it * 256];

  #pragma unroll
  for (int it = 0; it < 4; ++it) {
    const float4 qq = q[it];
    const u32 base = (u32)(t0 + it * 256) * 4u;
    if (qq.x >= THRV) { int p = atomicAdd(&lcnt, 1); if (p < LBUF) lbuf[p] = ((u64)__float_as_uint(qq.x) << 32) | (u64)(~(base      )); }
    if (qq.y >= THRV) { int p = atomicAdd(&lcnt, 1); if (p < LBUF) lbuf[p] = ((u64)__float_as_uint(qq.y) << 32) | (u64)(~(base + 1u)); }
    if (qq.z >= THRV) { int p = atomicAdd(&lcnt, 1); if (p < LBUF) lbuf[p] = ((u64)__float_as_uint(qq.z) << 32) | (u64)(~(base + 2u)); }
    if (qq.w >= THRV) { int p = atomicAdd(&lcnt, 1); if (p < LBUF) lbuf[p] = ((u64)__float_as_uint(qq.w) << 32) | (u64)(~(base + 3u)); }
  }
  __syncthreads();

  const int slot = b * BPB + blk;
  const int n = lcnt;
  const int wn = (n <= SLOT) ? n : SLOT;
  if (tid < wn) cand[(size_t)slot * SLOT + tid] = lbuf[tid];
  if (tid == 0) counts[slot] = (n <= SLOT) ? (u32)n : (u32)(SLOT + 1);  // >SLOT => exact fallback
}

// ---------------------------------------------------------------------------
// Node 2: one block per batch. Parallel scan of counts -> gather -> BUCKET
// rank-select (128 value-ordered buckets, ~7 keys each: kills the O(C) LDS
// broadcast inner loop that cost 31us in R6) -> sel + center-of-mass.
// Packed key (bits<<32)|~idx == jax.lax.top_k order (value desc, idx asc).
// Exact histogram fallback if the static threshold under/overflows.
// ---------------------------------------------------------------------------
__global__ __launch_bounds__(512) void k_select(const float* __restrict__ x,
                                                const u64* __restrict__ cand,
                                                const u32* __restrict__ counts,
                                                u64* __restrict__ sel,
                                                float* __restrict__ comvg) {
  const int b   = blockIdx.x;
  const int tid = threadIdx.x;

  __shared__ u64 lk[CAP];          // 32 KB (also the fallback histogram)
  __shared__ u64 lk2[CAP];         // 32 KB bucket-ordered keys
  __shared__ u64 sk[NPTS];
  __shared__ u32 sA[256], sB[256];
  __shared__ u32 scnt[BPB], spref[BPB];
  __shared__ u32 bc[NBUCK], bbx[NBUCK], bp[NBUCK], bA[NBUCK], bB[NBUCK];
  __shared__ float rbuf[8][4];
  __shared__ int sbad, sC;
  __shared__ u32 sthr;

  // ---- parallel scan of per-slot counts ----
  u32 myc = 0;
  if (tid == 0) sbad = 0;
  if (tid < 256) { myc = (tid < BPB) ? counts[b * BPB + tid] : 0u; sA[tid] = myc; }
  __syncthreads();
  if (tid < BPB && myc > SLOT) atomicOr(&sbad, 1);
  u32 *ssrc = sA, *sdst = sB;
  for (int off = 1; off < 256; off <<= 1) {
    if (tid < 256) sdst[tid] = ssrc[tid] + ((tid >= off) ? ssrc[tid - off] : 0u);
    __syncthreads();
    u32* t = ssrc; ssrc = sdst; sdst = t;
  }
  const int total = (int)ssrc[255];
  if (tid < BPB) { scnt[tid] = myc; spref[tid] = ssrc[tid] - myc; }
  __syncthreads();

  int C;
  if (!sbad && total >= NPTS && total <= CAP) {
    C = total;
    // gather slots into lk[0..C): 2 threads per slot
    for (int s = tid >> 1; s < BPB; s += 256) {
      const u32 c = scnt[s], p = spref[s];
      const u64* src = cand + (size_t)(b * BPB + s) * SLOT;
      for (u32 k = (u32)(tid & 1); k < c; k += 2) lk[p + k] = src[k];
    }
    __syncthreads();
  } else {
    // ---- exact fallback: fine histogram near 1.0 + re-collect ----
    u32* hist = reinterpret_cast<u32*>(lk);
    for (int i = tid; i < 4096; i += 512) hist[i] = 0u;
    __syncthreads();
    const u32* xb = reinterpret_cast<const u32*>(x) + (size_t)b * NVOX;
    for (int i = tid; i < NVOX; i += 512) {
      const u32 bits = xb[i];
      u32 key;
      if (bits >= 0x3F800000u) key = 0u;
      else { const u32 dd = THR_TOP - bits; key = dd >> 8; if (key > 4095u) key = 4095u; }
      atomicAdd(&hist[key], 1u);
    }
    __syncthreads();
    if (tid == 0) {
      u32 cum = 0; int kt = 4095;
      for (int k = 0; k < 4096; ++k) { cum += hist[k]; if (cum >= (u32)NPTS) { kt = k; break; } }
      sthr = (kt >= 4095) ? 0u : (0x3F800000u - ((u32)(kt + 1) << 8));
      sC = 0;
    }
    __syncthreads();
    const u32 thr = sthr;
    for (int i = tid; i < NVOX; i += 512) {
      const u32 bits = xb[i];
      if (bits >= thr) {
        const int p = atomicAdd(&sC, 1);
        if (p < CAP) lk[p] = ((u64)bits << 32) | (u64)(~(u32)i);
      }
    }
    __syncthreads();
    C = sC < CAP ? sC : CAP;
    __syncthreads();
  }

  // ---- bucket the keys by value stripe (bucket 0 = largest values) ----
  if (tid < NBUCK) bc[tid] = 0u;
  __syncthreads();
  for (int i = tid; i < C; i += 512) {
    const u32 bits = (u32)(lk[i] >> 32);
    u32 bk = (THR_TOP - bits) >> 7; if (bk > (NBUCK - 1)) bk = NBUCK - 1;  // clamp (fallback keys)
    atomicAdd(&bc[bk], 1u);
  }
  __syncthreads();
  if (tid < NBUCK) bA[tid] = bc[tid];
  __syncthreads();
  u32 *bsrc = bA, *bdst = bB;
  for (int off = 1; off < NBUCK; off <<= 1) {
    if (tid < NBUCK) bdst[tid] = bsrc[tid] + ((tid >= off) ? bsrc[tid - off] : 0u);
    __syncthreads();
    u32* t = bsrc; bsrc = bdst; bdst = t;
  }
  if (tid < NBUCK) { bbx[tid] = bsrc[tid] - bc[tid]; bp[tid] = bsrc[tid] - bc[tid]; }
  __syncthreads();
  // scatter into bucket order
  for (int i = tid; i < C; i += 512) {
    const u64 ki = lk[i];
    const u32 bits = (u32)(ki >> 32);
    u32 bk = (THR_TOP - bits) >> 7; if (bk > (NBUCK - 1)) bk = NBUCK - 1;
    const u32 p = atomicAdd(&bp[bk], 1u);
    lk2[p] = ki;
  }
  __syncthreads();
  // exact rank within bucket (keys unique: idx unique)
  for (int i = tid; i < C; i += 512) {
    const u64 ki = lk2[i];
    const u32 bits = (u32)(ki >> 32);
    u32 bk = (THR_TOP - bits) >> 7; if (bk > (NBUCK - 1)) bk = NBUCK - 1;
    const u32 lo = bbx[bk], hi = lo + bc[bk];
    int rank = (int)lo;
    for (u32 j = lo; j < hi; ++j) rank += (lk2[j] > ki) ? 1 : 0;
    if (rank < NPTS) sk[rank] = ki;
  }
  __syncthreads();

  const u64 key = sk[tid];
  sel[(size_t)b * NPTS + tid] = key;

  // ---- center of mass over the selected 512 ----
  const u32 bits = (u32)(key >> 32);
  const u32 idx  = ~((u32)key);
  const float v  = __uint_as_float(bits);
  const u32 z = idx / 9216u, rem = idx % 9216u, yy = rem / 96u, xw = rem % 96u;
  const float p0 = ((float)z  - 48.f) / 48.f;
  const float p1 = ((float)yy - 48.f) / 48.f;
  const float p2 = ((float)xw - 48.f) / 48.f;
  float sv = v, s0 = p0 * v, s1 = p1 * v, s2 = p2 * v;
  for (int off = 32; off > 0; off >>= 1) {
    sv += __shfl_down(sv, off);
    s0 += __shfl_down(s0, off);
    s1 += __shfl_down(s1, off);
    s2 += __shfl_down(s2, off);
  }
  const int w = tid >> 6, ln = tid & 63;
  if (ln == 0) { rbuf[w][0] = sv; rbuf[w][1] = s0; rbuf[w][2] = s1; rbuf[w][3] = s2; }
  __syncthreads();
  if (tid == 0) {
    float tv = 0.f, t0s = 0.f, t1s = 0.f, t2s = 0.f;
    for (int wv = 0; wv < 8; ++wv) { tv += rbuf[wv][0]; t0s += rbuf[wv][1]; t1s += rbuf[wv][2]; t2s += rbuf[wv][3]; }
    const float dnm = fmaxf(tv, 1e-12f);
    comvg[b * 4 + 0] = t0s / dnm; comvg[b * 4 + 1] = t1s / dnm;
    comvg[b * 4 + 2] = t2s / dnm; comvg[b * 4 + 3] = 0.f;
  }
}

// ---------------------------------------------------------------------------
// Node 3: 8 blocks per batch, 64 points each. 60-dim features (-> output)
// + collapsed scalar path (M built in-block) + partial max-pool -> ppart.
// Thread layout phase 1: (pl = tid>>3, cg = tid&7); phase 2: (g, vv).
// ---------------------------------------------------------------------------
__global__ __launch_bounds__(512) void k_featpool(const u64* __restrict__ sel,
                                                  const float* __restrict__ comvg,
                                                  const float* __restrict__ W1,
                                                  const float* __restrict__ W2,
                                                  const float* __restrict__ W3,
                                                  float* __restrict__ ppart,
                                                  float* __restrict__ dout) {
  const int p8  = blockIdx.x;
  const int b   = blockIdx.y;
  const int tid = threadIdx.x;
  __shared__ float Tm[16 * 64];
  __shared__ float Ms[16 * 128];
  __shared__ __align__(16) float fs[64][20];  // 80B rows: 16B-aligned float4 reads
  __shared__ float pr[4][128];

  // collapsed scalar-path matrix M = (W1_0e/4)(W2_0e/sqrt32)(W3_0e/8)
  const float s1c = 1.0f / (4.0f * sqrtf(32.0f));
  for (int e = tid; e < 16 * 64; e += 512) {
    const int u = e >> 6, j = e & 63;
    float s = 0.f;
    for (int k = 0; k < 32; ++k) s += W1[u * 32 + k] * W2[k * 64 + j];
    Tm[e] = s * s1c;
  }
  __syncthreads();
  for (int e = tid; e < 16 * 128; e += 512) {
    const int u = e >> 7, vv = e & 127;
    float s = 0.f;
    for (int j = 0; j < 64; ++j) s += Tm[u * 64 + j] * W3[j * 128 + vv];
    Ms[e] = s * 0.125f;
  }

  // ---- per-point features (8 threads per point compute redundantly) ----
  const int pl = tid >> 3, cg = tid & 7;
  const int gp = b * NPTS + p8 * 64 + pl;            // global point id
  const u64 key = sel[gp];
  const u32 bits = (u32)(key >> 32);
  const u32 idx  = ~((u32)key);
  const float v  = __uint_as_float(bits);
  const u32 z = idx / 9216u, rem = idx % 9216u, yy = rem / 96u, xw = rem % 96u;
  const float4 cm = reinterpret_cast<const float4*>(comvg)[b];
  const float c0 = ((float)z  - 48.f) / 48.f - cm.x;
  const float c1 = ((float)yy - 48.f) / 48.f - cm.y;
  const float c2 = ((float)xw - 48.f) / 48.f - cm.z;
  const float r = fmaxf(sqrtf(c0 * c0 + c1 * c1 + c2 * c2), 1e-6f);
  const float inv = 1.0f / r;
  const float d0 = c0 * inv, d1 = c1 * inv, d2 = c2 * inv;
  const float v2 = v * v;
  const float rr2 = r * r;
  const float l1 = log1pf(r);
  const float er = expf(-r);
  const float sgv = 1.0f / (1.0f + expf(-v));
  const float sgr = 1.0f / (1.0f + expf(-r));

  float f[60];
  f[0]=v;      f[1]=r;      f[2]=C0c;     f[3]=v*r;
  f[4]=v2;     f[5]=l1;     f[6]=sqrtf(v + 1e-6f); f[7]=rr2;
  f[8]=v*C0c;  f[9]=er;     f[10]=v2*v;   f[11]=sqrtf(r);
  f[12]=v*l1;  f[13]=sgv;   f[14]=sgr;    f[15]=v*rr2;
  f[16]=c0;        f[17]=c1;        f[18]=c2;
  f[19]=c0*v;      f[20]=c1*v;      f[21]=c2*v;
  f[22]=C1c*d0;    f[23]=C1c*d1;    f[24]=C1c*d2;
  f[25]=c0*r;      f[26]=c1*r;      f[27]=c2*r;
  f[28]=d0;        f[29]=d1;        f[30]=d2;
  f[31]=d0*v;      f[32]=d1*v;      f[33]=d2*v;
  f[34]=c0*v2;     f[35]=c1*v2;     f[36]=c2*v2;
  f[37]=C1c*d0*r;  f[38]=C1c*d1*r;  f[39]=C1c*d2*r;
  const float t0 = C2c * (SQ3c * d0 * d2);
  const float t1 = C2c * (SQ3c * d0 * d1);
  const float t2_ = C2c * (d1 * d1 - 0.5f * (d0 * d0 + d2 * d2));
  const float t3 = C2c * (SQ3c * d1 * d2);
  const float t4 = C2c * (0.5f * SQ3c * (d2 * d2 - d0 * d0));
  f[40]=t0;     f[41]=t1;     f[42]=t2_;     f[43]=t3;     f[44]=t4;
  f[45]=t0*v;   f[46]=t1*v;   f[47]=t2_*v;   f[48]=t3*v;   f[49]=t4*v;
  f[50]=t0*r;   f[51]=t1*r;   f[52]=t2_*r;   f[53]=t3*r;   f[54]=t4*r;
  f[55]=t0*l1;  f[56]=t1*l1;  f[57]=t2_*l1;  f[58]=t3*l1;  f[59]=t4*l1;

  // feat output: chunk k written by thread with cg == k&7 (compile-time f idx)
  float4* ob = reinterpret_cast<float4*>(dout + 16384 + (size_t)gp * 60);
  #pragma unroll
  for (int k = 0; k < 15; ++k)
    if ((k & 7) == cg) ob[k] = make_float4(f[4*k], f[4*k+1], f[4*k+2], f[4*k+3]);

  // stage the 16 scalar features to LDS (cg 0..3 write one float4 each)
  #pragma unroll
  for (int k = 0; k < 4; ++k)
    if (k == cg) *reinterpret_cast<float4*>(&fs[pl][k * 4]) =
        make_float4(f[4*k], f[4*k+1], f[4*k+2], f[4*k+3]);
  __syncthreads();

  // ---- partial pool: h3 = fs @ Ms, max over this block's 64 points ----
  const int g = tid >> 7, vv = tid & 127;
  float mreg[16];
  #pragma unroll
  for (int u = 0; u < 16; ++u) mreg[u] = Ms[u * 128 + vv];
  float pm = -3.4e38f;
  for (int n = g; n < 64; n += 4) {
    const float4 a0 = *reinterpret_cast<const float4*>(&fs[n][0]);
    const float4 a1 = *reinterpret_cast<const float4*>(&fs[n][4]);
    const float4 a2 = *reinterpret_cast<const float4*>(&fs[n][8]);
    const float4 a3 = *reinterpret_cast<const float4*>(&fs[n][12]);
    float acc = a0.x*mreg[0] + a0.y*mreg[1] + a0.z*mreg[2] + a0.w*mreg[3]
              + a1.x*mreg[4] + a1.y*mreg[5] + a1.z*mreg[6] + a1.w*mreg[7]
              + a2.x*mreg[8] + a2.y*mreg[9] + a2.z*mreg[10]+ a2.w*mreg[11]
              + a3.x*mreg[12]+ a3.y*mreg[13]+ a3.z*mreg[14]+ a3.w*mreg[15];
    pm = fmaxf(pm, acc);
  }
  pr[g][vv] = pm;
  __syncthreads();
  if (g == 0)
    ppart[((size_t)b * 8 + p8) * 128 + vv] =
        fmaxf(fmaxf(pr[0][vv], pr[1][vv]), fmaxf(pr[2][vv], pr[3][vv]));
}

// ---------------------------------------------------------------------------
// Node 4: reduce the 8 pooled partials per batch + head MLP -> logits.
// ---------------------------------------------------------------------------
__global__ __launch_bounds__(512) void k_head(const float* __restrict__ ppart,
                                              const float* __restrict__ fc1w,
                                              const float* __restrict__ fc1b,
                                              const float* __restrict__ fc2w,
                                              const float* __restrict__ fc2b,
                                              float* __restrict__ dout) {
  const int b = blockIdx.x;
  const int t = threadIdx.x;
  __shared__ float pl[128];
  __shared__ float hid[64];
  if (t < 128) {
    float m = -3.4e38f;
    #pragma unroll
    for (int k = 0; k < 8; ++k) m = fmaxf(m, ppart[((size_t)b * 8 + k) * 128 + t]);
    pl[t] = m;
  }
  __syncthreads();
  if (t < 64) {
    float sh = fc1b[t];
    for (int u = 0; u < 128; ++u) sh += pl[u] * fc1w[u * 64 + t];
    hid[t] = fmaxf(sh, 0.f);
  }
  __syncthreads();
  float sl = fc2b[t];
  for (int j = 0; j < 64; ++j) sl += hid[j] * fc2w[j * 512 + t];
  dout[b * 512 + t] = sl;
}

extern "C" void kernel_launch(void* const* d_in, const int* in_sizes, int n_in,
                              void* d_out, int out_size, void* d_ws, size_t ws_size,
                              hipStream_t stream) {
  const float* x    = (const float*)d_in[0];
  const float* W1   = (const float*)d_in[1];   // W1_0e (16,32)
  const float* W2   = (const float*)d_in[4];   // W2_0e (32,64)
  const float* W3   = (const float*)d_in[7];   // W3_0e (64,128)
  const float* fc1w = (const float*)d_in[8];
  const float* fc1b = (const float*)d_in[9];
  const float* fc2w = (const float*)d_in[10];
  const float* fc2b = (const float*)d_in[11];
  float* out = (float*)d_out;

  // workspace layout (~4.6 MB); every read location is rewritten earlier in
  // the same call -> no cross-replay state, poison-safe.
  uint8_t* ws = (uint8_t*)d_ws;
  u32*   counts = (u32*)ws;                     // 6912 u32
  u64*   cand   = (u64*)(ws + 0x10000);         // 6912*64*8 = 3.54 MB
  u64*   sel    = (u64*)(ws + 0x400000);        // 32*512*8 = 128 KB
  float* comv   = (float*)(ws + 0x420000);      // 32 float4
  float* ppart  = (float*)(ws + 0x421000);      // 32*8*128 f32 = 128 KB

  dim3 g1(BPB, NB);
  k_collect<<<g1, 256, 0, stream>>>(x, cand, counts);
  k_select<<<NB, 512, 0, stream>>>(x, cand, counts, sel, comv);
  dim3 g3(8, NB);
  k_featpool<<<g3, 512, 0, stream>>>(sel, comv, W1, W2, W3, ppart, out);
  k_head<<<NB, 512, 0, stream>>>(ppart, fc1w, fc1b, fc2w, fc2b, out);
}